// Round 4
// baseline (1190.719 us; speedup 1.0000x reference)
//
#include <hip/hip_runtime.h>
#include <math.h>

// RBF mixture: out[i] = sum_m w_m * exp(-(x_i-mu_m)^T C_m (x_i-mu_m)), C_m = G_m G_m^T
// N=32768, M=2048, D=32.
// Round 4: (a) symmetric packing K=1088->576 (upper triangle, 2*C_df off-diag),
// (b) XCD-aware block remap so each XCD keeps one A-tile in its L2 while
// sweeping all m-tiles, (c) survivor compaction: screen epilogue pushes (i,m)
// pairs to a global list; separate kernel does exact fp32 recompute.

#define NN 32768
#define MM 2048
#define DDIM 32
#define KSYM 576           // 528 triangle + 32 cross + 2 const + 14 pad = 9*64
#define SCREEN 256.0f
#define CAP 2000000

typedef __attribute__((ext_vector_type(8))) short short8;
typedef __attribute__((ext_vector_type(4))) float floatx4;

__device__ __forceinline__ unsigned int to_bf16(float f) {
  union { float f; unsigned int u; } x; x.f = f;
  return (x.u + 0x7fffu + ((x.u >> 16) & 1u)) >> 16;   // RNE, finite inputs only
}

// slot s in [0,528) -> (d,f), d<=f, order: d ascending, f=d..31
__device__ __forceinline__ void slot_df(int s, int* dd, int* ff) {
  int d = 0, b = 0;
  while (b + (DDIM - d) <= s) { b += DDIM - d; ++d; }
  *dd = d; *ff = d + (s - b);
}

// ---------------------------------------------------------------------------
// Kernel 1: bf16 B-matrix [M][KSYM]:
//  [0,528): C_dd diag / 2*C_df offdiag; [528,560): -2*(C mu)_d;
//  560: c_hi, 561: c_lo (c = mu^T C mu); [562,576): 0
// ---------------------------------------------------------------------------
__global__ __launch_bounds__(256) void build_b_kernel(
    const float* __restrict__ gamma, const float* __restrict__ means,
    unsigned short* __restrict__ Bm) {
  __shared__ float G[DDIM][DDIM + 1];
  __shared__ float C[DDIM][DDIM + 1];
  __shared__ float bv[DDIM];
  __shared__ float cc;
  const int m = blockIdx.x;
  const int t = threadIdx.x;
  const float* g = gamma + (size_t)m * DDIM * DDIM;
  for (int l = t; l < DDIM * DDIM; l += 256) G[l >> 5][l & 31] = g[l];
  __syncthreads();
  const float* mu = means + m * DDIM;
  for (int l = t; l < DDIM * DDIM; l += 256) {
    int d = l >> 5, f = l & 31;
    float c = 0.f;
#pragma unroll
    for (int e = 0; e < DDIM; ++e) c += G[d][e] * G[f][e];
    C[d][f] = c;
  }
  __syncthreads();
  if (t < DDIM) {
    float b = 0.f;
#pragma unroll
    for (int f = 0; f < DDIM; ++f) b += C[t][f] * mu[f];
    bv[t] = b;
  }
  __syncthreads();
  if (t == 0) {
    float c = 0.f;
#pragma unroll
    for (int d = 0; d < DDIM; ++d) c += bv[d] * mu[d];
    cc = c;
  }
  __syncthreads();
  unsigned short* brow = Bm + (size_t)m * KSYM;
  for (int s = t; s < KSYM; s += 256) {
    float val;
    if (s < 528) {
      int d, f; slot_df(s, &d, &f);
      val = (d == f) ? C[d][d] : 2.f * C[d][f];
    } else if (s < 560) {
      val = -2.f * bv[s - 528];
    } else if (s == 560) {
      val = cc;                      // hi part; lo fixed below
    } else if (s == 561) {
      unsigned int hi = to_bf16(cc);
      union { unsigned int u; float f; } xh; xh.u = hi << 16;
      val = cc - xh.f;
    } else {
      val = 0.f;
    }
    brow[s] = (unsigned short)to_bf16(val);
  }
}

// ---------------------------------------------------------------------------
// Kernel 2: bf16 A-matrix chunk [rows][KSYM]:
//  [0,528): x_d*x_f (d<=f); [528,560): x_d; 560,561: 1.0; pad 0
// 64 rows/block, 4 threads/row, slot->(d,f) table in LDS.
// xs row has [32]=1.0, [33]=0.0 so table handles tail slots uniformly.
// ---------------------------------------------------------------------------
__global__ __launch_bounds__(256) void build_a_kernel(
    const float* __restrict__ x, unsigned short* __restrict__ Am) {
  __shared__ float xs[64][36];
  __shared__ unsigned char sd[KSYM], sf[KSYM];
  const int t = threadIdx.x;
  const int r0 = blockIdx.x * 64;
#pragma unroll
  for (int it = 0; it < 2; ++it) {
    int l = it * 256 + t;
    int r = l >> 3, q = l & 7;
    floatx4 v = *(const floatx4*)(x + (size_t)(r0 + r) * DDIM + q * 4);
    *(floatx4*)&xs[r][q * 4] = v;
  }
  if (t < 64) { xs[t][32] = 1.f; xs[t][33] = 0.f; }
  for (int l = t; l < KSYM; l += 256) {
    int d, f;
    if (l < 528)      { slot_df(l, &d, &f); }
    else if (l < 560) { d = l - 528; f = 32; }
    else if (l < 562) { d = 32; f = 32; }
    else              { d = 33; f = 33; }
    sd[l] = (unsigned char)d; sf[l] = (unsigned char)f;
  }
  __syncthreads();
  const int r = t >> 2, j = t & 3;
  const float* xr = &xs[r][0];
  unsigned short* arow = Am + (size_t)(r0 + r) * KSYM + j * 144;
#pragma unroll 2
  for (int ss = 0; ss < 144; ss += 8) {
    int s0 = j * 144 + ss;
    uint4 o;
    unsigned int u[4];
#pragma unroll
    for (int q = 0; q < 4; ++q) {
      int sA = s0 + 2 * q;
      float v0 = xr[sd[sA]] * xr[sf[sA]];
      float v1 = xr[sd[sA + 1]] * xr[sf[sA + 1]];
      u[q] = to_bf16(v0) | (to_bf16(v1) << 16);
    }
    o.x = u[0]; o.y = u[1]; o.z = u[2]; o.w = u[3];
    *(uint4*)(arow + ss) = o;
  }
}

// ---------------------------------------------------------------------------
// Exact path (fp32, no cancellation; double accumulate).
// ---------------------------------------------------------------------------
__device__ __noinline__ double survivor_contrib(
    int m, const float* __restrict__ gamma, const float* __restrict__ means,
    const float* __restrict__ weights, const float* __restrict__ xrow) {
  const float* mu = means + m * DDIM;
  float v[DDIM];
#pragma unroll
  for (int d = 0; d < DDIM; ++d) v[d] = xrow[d] - mu[d];
  const float* g = gamma + (size_t)m * DDIM * DDIM;
  float Dex = 0.f;
  for (int e = 0; e < DDIM; ++e) {
    float y = 0.f;
#pragma unroll
    for (int d = 0; d < DDIM; ++d) y += g[d * DDIM + e] * v[d];
    Dex += y * y;
  }
  return (double)weights[m] * exp(-(double)Dex);
}

// ---------------------------------------------------------------------------
// Kernel 3: bf16 MFMA screen GEMM, 128x128 tile, BK=64, K=576 (9 iters).
// XCD-aware remap: linear -> chunks of 128 blocks (8 i-tiles x 16 m-tiles,
// i fastest) so XCD j (= linear%8) keeps i-tile j's A rows (144 KB) in its L2
// across all 16 m-tiles. global_load_lds width-16; XOR chunk swizzle (0
// conflicts, verified r3). Epilogue: push survivors to compacted list.
// ---------------------------------------------------------------------------
__global__ __launch_bounds__(256) void screen_kernel(
    const unsigned short* __restrict__ Am, const float* __restrict__ x,
    const float* __restrict__ gamma, const float* __restrict__ means,
    const float* __restrict__ weights, const unsigned short* __restrict__ Bm,
    double* __restrict__ acc_out, unsigned int* __restrict__ list,
    unsigned int* __restrict__ count, int i_base) {
  __shared__ unsigned short As[128 * 64];
  __shared__ unsigned short Bs[128 * 64];
  const int t = threadIdx.x;
  const int linear = blockIdx.y * 16 + blockIdx.x;
  const int chunk = linear >> 7, idx128 = linear & 127;
  const int m_blk = idx128 >> 3, i_loc = idx128 & 7;
  const int i_blk = chunk * 8 + i_loc;
  const int i0 = i_blk * 128;          // chunk-local row base
  const int m0 = m_blk * 128;
  const int lane = t & 63, w = t >> 6;
  const int wm = w >> 1, wn = w & 1;
  const int lrow = lane & 15, quad = lane >> 4;
  const int srow = lane >> 3, sslot = lane & 7;

  floatx4 acc[4][4] = {};

  for (int kc = 0; kc < 9; ++kc) {
#pragma unroll
    for (int p = 0; p < 4; ++p) {
      const int rb = p * 32 + w * 8;               // wave-uniform row base
      const int r = rb + srow;
      const int c = sslot ^ (r & 7);               // swizzled source chunk
      const unsigned short* gA = Am + (size_t)(i0 + r) * KSYM + kc * 64 + c * 8;
      const unsigned short* gB = Bm + (size_t)(m0 + r) * KSYM + kc * 64 + c * 8;
      __builtin_amdgcn_global_load_lds(
          (const __attribute__((address_space(1))) void*)gA,
          (__attribute__((address_space(3))) void*)(As + (size_t)rb * 64), 16, 0, 0);
      __builtin_amdgcn_global_load_lds(
          (const __attribute__((address_space(1))) void*)gB,
          (__attribute__((address_space(3))) void*)(Bs + (size_t)rb * 64), 16, 0, 0);
    }
    __syncthreads();
#pragma unroll
    for (int kk = 0; kk < 2; ++kk) {
      short8 af[4], bfv[4];
#pragma unroll
      for (int ti = 0; ti < 4; ++ti) {
        int ar = wm * 64 + ti * 16 + lrow;
        int slot = (kk * 4 + quad) ^ (ar & 7);
        af[ti] = *(const short8*)&As[ar * 64 + slot * 8];
      }
#pragma unroll
      for (int tj = 0; tj < 4; ++tj) {
        int br = wn * 64 + tj * 16 + lrow;
        int slot = (kk * 4 + quad) ^ (br & 7);
        bfv[tj] = *(const short8*)&Bs[br * 64 + slot * 8];
      }
#pragma unroll
      for (int ti = 0; ti < 4; ++ti)
#pragma unroll
        for (int tj = 0; tj < 4; ++tj)
          acc[ti][tj] = __builtin_amdgcn_mfma_f32_16x16x32_bf16(
              af[ti], bfv[tj], acc[ti][tj], 0, 0, 0);
    }
    __syncthreads();
  }

  // epilogue: compact survivors (rare) to global list; inline fallback if full
#pragma unroll
  for (int ti = 0; ti < 4; ++ti) {
#pragma unroll
    for (int tj = 0; tj < 4; ++tj) {
#pragma unroll
      for (int r = 0; r < 4; ++r) {
        float Dt = acc[ti][tj][r];
        if (Dt < SCREEN) {
          int gi = i_base + i0 + wm * 64 + ti * 16 + quad * 4 + r;
          int gm = m0 + wn * 64 + tj * 16 + lrow;
          unsigned int idx = atomicAdd(count, 1u);
          if (idx < CAP) {
            list[idx] = ((unsigned int)gi << 11) | (unsigned int)gm;
          } else {
            double c = survivor_contrib(gm, gamma, means, weights,
                                        x + (size_t)gi * DDIM);
            atomicAdd(&acc_out[gi], c);
          }
        }
      }
    }
  }
}

// ---------------------------------------------------------------------------
// Kernel 4: process compacted survivor list (exact fp32 recompute).
// ---------------------------------------------------------------------------
__global__ __launch_bounds__(256) void survivor_kernel(
    const unsigned int* __restrict__ list, const unsigned int* __restrict__ count,
    const float* __restrict__ x, const float* __restrict__ gamma,
    const float* __restrict__ means, const float* __restrict__ weights,
    double* __restrict__ acc_out) {
  unsigned int total = *count;
  if (total > CAP) total = CAP;
  for (unsigned int idx = blockIdx.x * 256 + threadIdx.x; idx < total;
       idx += gridDim.x * 256) {
    unsigned int p = list[idx];
    int gi = (int)(p >> 11), gm = (int)(p & 2047u);
    double c = survivor_contrib(gm, gamma, means, weights,
                                x + (size_t)gi * DDIM);
    atomicAdd(&acc_out[gi], c);
  }
}

__global__ __launch_bounds__(256) void finalize_kernel(
    const double* __restrict__ acc, float* __restrict__ out) {
  int i = blockIdx.x * 256 + threadIdx.x;
  out[i] = (float)acc[i];
}

extern "C" void kernel_launch(void* const* d_in, const int* in_sizes, int n_in,
                              void* d_out, int out_size, void* d_ws, size_t ws_size,
                              hipStream_t stream) {
  (void)in_sizes; (void)n_in; (void)out_size;
  const float* x       = (const float*)d_in[0];   // [N][32]
  const float* gamma   = (const float*)d_in[1];   // [M][32][32]
  const float* means   = (const float*)d_in[2];   // [M][32]
  const float* weights = (const float*)d_in[3];   // [M]

  char* p = (char*)d_ws;
  double* acc          = (double*)p;            p += (size_t)NN * 8;
  unsigned int* count  = (unsigned int*)p;      p += 16;
  unsigned int* list   = (unsigned int*)p;      p += (size_t)CAP * 4;
  unsigned short* Bm   = (unsigned short*)p;    p += (size_t)MM * KSYM * 2;
  unsigned short* Am   = (unsigned short*)p;
  const size_t fixed = (size_t)(p - (char*)d_ws);
  if (ws_size < fixed + (size_t)1024 * KSYM * 2) return;

  size_t avail = ws_size - fixed;
  long rows_cap = (long)(avail / ((size_t)KSYM * 2));
  rows_cap = (rows_cap / 1024) * 1024;          // grid y must be multiple of 8
  if (rows_cap > NN) rows_cap = NN;

  hipMemsetAsync(acc, 0, (size_t)NN * 8 + 16, stream);   // acc + count
  hipLaunchKernelGGL(build_b_kernel, dim3(MM), dim3(256), 0, stream, gamma, means, Bm);
  for (long i0 = 0; i0 < NN; i0 += rows_cap) {
    long rows = (NN - i0 < rows_cap) ? (NN - i0) : rows_cap;
    hipLaunchKernelGGL(build_a_kernel, dim3(rows / 64), dim3(256), 0, stream,
                       x + (size_t)i0 * DDIM, Am);
    hipLaunchKernelGGL(screen_kernel, dim3(16, rows / 128), dim3(256), 0, stream,
                       Am, x, gamma, means, weights, Bm, acc, list, count, (int)i0);
  }
  hipLaunchKernelGGL(survivor_kernel, dim3(128), dim3(256), 0, stream,
                     list, count, x, gamma, means, weights, acc);
  hipLaunchKernelGGL(finalize_kernel, dim3(NN / 256), dim3(256), 0, stream,
                     acc, (float*)d_out);
}

// Round 5
// 348.424 us; speedup vs baseline: 3.4174x; 3.4174x over previous
//
#include <hip/hip_runtime.h>
#include <math.h>

// RBF mixture: out[i] = sum_m w_m * exp(-(x_i-mu_m)^T C_m (x_i-mu_m)), C_m = G_m G_m^T
// N=32768, M=2048, D=32.
// Round 5: barrier-free screen GEMM. Per block: 64-row A-tile (K=576 packed
// symmetric form) resident in 73.7 KB dynamic LDS, loaded once; waves sweep
// all M with B fragments loaded global->VGPR (B = 2.36 MB, L2-resident),
// 4 m-subtiles in flight, 2-deep software pipeline, zero K-loop barriers.
// Survivors (D~ < SCREEN; exp underflows fp32 at D>104) -> compact list ->
// exact fp32 recompute kernel.

#define NN 32768
#define MM 2048
#define DDIM 32
#define KSYM 576           // 528 triangle + 32 cross + 2 const + 14 pad = 18*32
#define ROWS 64            // i-rows per screen block
#define KSTEPS 18
#define SCREEN 160.0f
#define CAP 2000000

typedef __attribute__((ext_vector_type(8))) short short8;
typedef __attribute__((ext_vector_type(4))) float floatx4;

__device__ __forceinline__ unsigned int to_bf16(float f) {
  union { float f; unsigned int u; } x; x.f = f;
  return (x.u + 0x7fffu + ((x.u >> 16) & 1u)) >> 16;   // RNE, finite inputs only
}

// slot s in [0,528) -> (d,f), d<=f (runtime version, build_b only)
__device__ __forceinline__ void slot_df(int s, int* dd, int* ff) {
  int d = 0, b = 0;
  while (b + (DDIM - d) <= s) { b += DDIM - d; ++d; }
  *dd = d; *ff = d + (s - b);
}

// ---------------------------------------------------------------------------
// Kernel 1: bf16 B-matrix [M][KSYM]:
//  [0,528): C_dd diag / 2*C_df offdiag (triangle, d-major); [528,560): -2*(C mu);
//  560: c_hi, 561: c_lo (c = mu^T C mu); [562,576): 0
// ---------------------------------------------------------------------------
__global__ __launch_bounds__(256) void build_b_kernel(
    const float* __restrict__ gamma, const float* __restrict__ means,
    unsigned short* __restrict__ Bm) {
  __shared__ float G[DDIM][DDIM + 1];
  __shared__ float C[DDIM][DDIM + 1];
  __shared__ float bv[DDIM];
  __shared__ float cc;
  const int m = blockIdx.x;
  const int t = threadIdx.x;
  const float* g = gamma + (size_t)m * DDIM * DDIM;
  for (int l = t; l < DDIM * DDIM; l += 256) G[l >> 5][l & 31] = g[l];
  __syncthreads();
  const float* mu = means + m * DDIM;
  for (int l = t; l < DDIM * DDIM; l += 256) {
    int d = l >> 5, f = l & 31;
    float c = 0.f;
#pragma unroll
    for (int e = 0; e < DDIM; ++e) c += G[d][e] * G[f][e];
    C[d][f] = c;
  }
  __syncthreads();
  if (t < DDIM) {
    float b = 0.f;
#pragma unroll
    for (int f = 0; f < DDIM; ++f) b += C[t][f] * mu[f];
    bv[t] = b;
  }
  __syncthreads();
  if (t == 0) {
    float c = 0.f;
#pragma unroll
    for (int d = 0; d < DDIM; ++d) c += bv[d] * mu[d];
    cc = c;
  }
  __syncthreads();
  unsigned short* brow = Bm + (size_t)m * KSYM;
  for (int s = t; s < KSYM; s += 256) {
    float val;
    if (s < 528) {
      int d, f; slot_df(s, &d, &f);
      val = (d == f) ? C[d][d] : 2.f * C[d][f];
    } else if (s < 560) {
      val = -2.f * bv[s - 528];
    } else if (s == 560) {
      val = cc;
    } else if (s == 561) {
      unsigned int hi = to_bf16(cc);
      union { unsigned int u; float f; } xh; xh.u = hi << 16;
      val = cc - xh.f;
    } else {
      val = 0.f;
    }
    brow[s] = (unsigned short)to_bf16(val);
  }
}

// ---------------------------------------------------------------------------
// Kernel 2: bf16 A-matrix [rows][KSYM]. One thread per row; (d,f) fully
// compile-time via unrolled nested loops -> register-only, no LDS, no
// divergence. Layout matches build_b's triangle order exactly.
// ---------------------------------------------------------------------------
__global__ __launch_bounds__(256) void build_a_kernel(
    const float* __restrict__ x, unsigned short* __restrict__ Am) {
  const int row = blockIdx.x * 256 + threadIdx.x;
  float v[DDIM];
#pragma unroll
  for (int q = 0; q < 8; ++q)
    *(floatx4*)&v[q * 4] = *(const floatx4*)(x + (size_t)row * DDIM + q * 4);
  unsigned short* arow = Am + (size_t)row * KSYM;
  unsigned int u0 = 0, u1 = 0, u2 = 0, u3 = 0;
  int s = 0;
#pragma unroll
  for (int d = 0; d < DDIM; ++d) {
#pragma unroll
    for (int f = d; f < DDIM; ++f) {
      unsigned int b = to_bf16(v[d] * v[f]);
      int sl = (s & 7) >> 1;
      unsigned int add = ((s & 1) == 0) ? b : (b << 16);
      if (sl == 0) u0 = ((s & 1) == 0) ? add : (u0 | add);
      else if (sl == 1) u1 = ((s & 1) == 0) ? add : (u1 | add);
      else if (sl == 2) u2 = ((s & 1) == 0) ? add : (u2 | add);
      else              u3 = ((s & 1) == 0) ? add : (u3 | add);
      if ((s & 7) == 7) {
        uint4 o; o.x = u0; o.y = u1; o.z = u2; o.w = u3;
        *(uint4*)(arow + (s - 7)) = o;
      }
      ++s;
    }
  }
  // s == 528 here (divisible by 8): cross terms x_f
#pragma unroll
  for (int f = 0; f < DDIM; f += 8) {
    uint4 o;
    o.x = to_bf16(v[f + 0]) | (to_bf16(v[f + 1]) << 16);
    o.y = to_bf16(v[f + 2]) | (to_bf16(v[f + 3]) << 16);
    o.z = to_bf16(v[f + 4]) | (to_bf16(v[f + 5]) << 16);
    o.w = to_bf16(v[f + 6]) | (to_bf16(v[f + 7]) << 16);
    *(uint4*)(arow + 528 + f) = o;
  }
  uint4 one; one.x = 0x3f803f80u; one.y = 0u; one.z = 0u; one.w = 0u;
  *(uint4*)(arow + 560) = one;
  uint4 z; z.x = 0u; z.y = 0u; z.z = 0u; z.w = 0u;
  *(uint4*)(arow + 568) = z;
}

// ---------------------------------------------------------------------------
// Exact path (fp32, no cancellation; double accumulate).
// ---------------------------------------------------------------------------
__device__ __noinline__ double survivor_contrib(
    int m, const float* __restrict__ gamma, const float* __restrict__ means,
    const float* __restrict__ weights, const float* __restrict__ xrow) {
  const float* mu = means + m * DDIM;
  float v[DDIM];
#pragma unroll
  for (int d = 0; d < DDIM; ++d) v[d] = xrow[d] - mu[d];
  const float* g = gamma + (size_t)m * DDIM * DDIM;
  float Dex = 0.f;
  for (int e = 0; e < DDIM; ++e) {
    float y = 0.f;
#pragma unroll
    for (int d = 0; d < DDIM; ++d) y += g[d * DDIM + e] * v[d];
    Dex += y * y;
  }
  return (double)weights[m] * exp(-(double)Dex);
}

// ---------------------------------------------------------------------------
// Kernel 3: barrier-free bf16 MFMA screen. Block = 256 thr (4 waves), 64-row
// A-tile in dynamic LDS (XOR chunk swizzle -> b128 reads at the 8-addr/bank
// floor). Wave w sweeps m-quads {8g+... : q = g*4+w}, 4 m-subtiles in flight,
// B frags global->VGPR (L2-resident), 2-deep k pipeline, no __syncthreads in
// the sweep. Frag layout (m89/m97-verified): A/B [row=lane&15][k=quad*8+j];
// C/D col=lane&15, row=quad*4+reg.
// ---------------------------------------------------------------------------
__global__ __launch_bounds__(256, 2) void screen_kernel(
    const unsigned short* __restrict__ Am, const float* __restrict__ x,
    const float* __restrict__ gamma, const float* __restrict__ means,
    const float* __restrict__ weights, const unsigned short* __restrict__ Bm,
    double* __restrict__ acc_out, unsigned int* __restrict__ list,
    unsigned int* __restrict__ count, int i_base) {
  extern __shared__ __align__(16) unsigned short As[];   // ROWS * KSYM
  const int t = threadIdx.x;
  const int i0 = blockIdx.x * ROWS;
  const int lane = t & 63, w = t >> 6;
  const int lrow = lane & 15, quad = lane >> 4;

  // stage A tile once: 64 rows x 72 chunks(16B); swizzle slot = c^(r&7) in 8-groups
#pragma unroll
  for (int it = 0; it < 18; ++it) {
    int g = it * 256 + t;
    int r = g / 72, c = g - r * 72;
    uint4 v = *(const uint4*)(Am + (size_t)(i0 + r) * KSYM + c * 8);
    int cs = (c & ~7) | ((c & 7) ^ (r & 7));
    *(uint4*)&As[r * KSYM + cs * 8] = v;
  }
  __syncthreads();

  for (int g8 = 0; g8 < 8; ++g8) {
    const int m0 = (g8 * 4 + w) * 64;               // this wave's m-quad base
    const unsigned short* bb0 = Bm + (size_t)(m0 +  0 + lrow) * KSYM + quad * 8;
    const unsigned short* bb1 = Bm + (size_t)(m0 + 16 + lrow) * KSYM + quad * 8;
    const unsigned short* bb2 = Bm + (size_t)(m0 + 32 + lrow) * KSYM + quad * 8;
    const unsigned short* bb3 = Bm + (size_t)(m0 + 48 + lrow) * KSYM + quad * 8;

    floatx4 acc[4][4] = {};                          // [ti][mj]
    short8 af[2][4], bf[2][4];
#pragma unroll
    for (int ti = 0; ti < 4; ++ti) {
      int r = ti * 16 + lrow;
      int cs = (quad & 7) ^ (r & 7);                 // kk=0: c = quad
      af[0][ti] = *(const short8*)&As[r * KSYM + cs * 8];
    }
    bf[0][0] = *(const short8*)bb0;
    bf[0][1] = *(const short8*)bb1;
    bf[0][2] = *(const short8*)bb2;
    bf[0][3] = *(const short8*)bb3;

#pragma unroll
    for (int kk = 0; kk < KSTEPS; ++kk) {
      const int cur = kk & 1, nxt = cur ^ 1;
      if (kk + 1 < KSTEPS) {
        bf[nxt][0] = *(const short8*)(bb0 + (kk + 1) * 32);
        bf[nxt][1] = *(const short8*)(bb1 + (kk + 1) * 32);
        bf[nxt][2] = *(const short8*)(bb2 + (kk + 1) * 32);
        bf[nxt][3] = *(const short8*)(bb3 + (kk + 1) * 32);
#pragma unroll
        for (int ti = 0; ti < 4; ++ti) {
          int r = ti * 16 + lrow;
          int c = (kk + 1) * 4 + quad;
          int cs = (c & ~7) | ((c & 7) ^ (r & 7));
          af[nxt][ti] = *(const short8*)&As[r * KSYM + cs * 8];
        }
      }
#pragma unroll
      for (int ti = 0; ti < 4; ++ti)
#pragma unroll
        for (int mj = 0; mj < 4; ++mj)
          acc[ti][mj] = __builtin_amdgcn_mfma_f32_16x16x32_bf16(
              af[cur][ti], bf[cur][mj], acc[ti][mj], 0, 0, 0);
    }

    // screen & emit survivors (rare)
#pragma unroll
    for (int ti = 0; ti < 4; ++ti)
#pragma unroll
      for (int mj = 0; mj < 4; ++mj)
#pragma unroll
        for (int r = 0; r < 4; ++r) {
          float Dt = acc[ti][mj][r];
          if (Dt < SCREEN) {
            int gi = i_base + i0 + ti * 16 + quad * 4 + r;
            int gm = m0 + mj * 16 + lrow;
            unsigned int idx = atomicAdd(count, 1u);
            if (idx < CAP) {
              list[idx] = ((unsigned int)gi << 11) | (unsigned int)gm;
            } else {
              double c = survivor_contrib(gm, gamma, means, weights,
                                          x + (size_t)gi * DDIM);
              atomicAdd(&acc_out[gi], c);
            }
          }
        }
  }
}

// ---------------------------------------------------------------------------
// Kernel 4: process compacted survivor list (exact fp32 recompute).
// ---------------------------------------------------------------------------
__global__ __launch_bounds__(256) void survivor_kernel(
    const unsigned int* __restrict__ list, const unsigned int* __restrict__ count,
    const float* __restrict__ x, const float* __restrict__ gamma,
    const float* __restrict__ means, const float* __restrict__ weights,
    double* __restrict__ acc_out) {
  unsigned int total = *count;
  if (total > CAP) total = CAP;
  for (unsigned int idx = blockIdx.x * 256 + threadIdx.x; idx < total;
       idx += gridDim.x * 256) {
    unsigned int p = list[idx];
    int gi = (int)(p >> 11), gm = (int)(p & 2047u);
    double c = survivor_contrib(gm, gamma, means, weights,
                                x + (size_t)gi * DDIM);
    atomicAdd(&acc_out[gi], c);
  }
}

__global__ __launch_bounds__(256) void finalize_kernel(
    const double* __restrict__ acc, float* __restrict__ out) {
  int i = blockIdx.x * 256 + threadIdx.x;
  out[i] = (float)acc[i];
}

extern "C" void kernel_launch(void* const* d_in, const int* in_sizes, int n_in,
                              void* d_out, int out_size, void* d_ws, size_t ws_size,
                              hipStream_t stream) {
  (void)in_sizes; (void)n_in; (void)out_size;
  const float* x       = (const float*)d_in[0];   // [N][32]
  const float* gamma   = (const float*)d_in[1];   // [M][32][32]
  const float* means   = (const float*)d_in[2];   // [M][32]
  const float* weights = (const float*)d_in[3];   // [M]

  char* p = (char*)d_ws;
  double* acc          = (double*)p;            p += (size_t)NN * 8;
  unsigned int* count  = (unsigned int*)p;      p += 16;
  unsigned int* list   = (unsigned int*)p;      p += (size_t)CAP * 4;
  unsigned short* Bm   = (unsigned short*)p;    p += (size_t)MM * KSYM * 2;
  unsigned short* Am   = (unsigned short*)p;
  const size_t fixed = (size_t)(p - (char*)d_ws);
  if (ws_size < fixed + (size_t)256 * KSYM * 2) return;

  size_t avail = ws_size - fixed;
  long rows_cap = (long)(avail / ((size_t)KSYM * 2));
  rows_cap = (rows_cap / 256) * 256;            // build_a uses 256-row blocks
  if (rows_cap > NN) rows_cap = NN;

  // allow 73.7 KB dynamic LDS for the screen kernel (host-side, capture-safe)
  (void)hipFuncSetAttribute((const void*)screen_kernel,
                            hipFuncAttributeMaxDynamicSharedMemorySize,
                            ROWS * KSYM * 2);

  hipMemsetAsync(acc, 0, (size_t)NN * 8 + 16, stream);   // acc + count
  hipLaunchKernelGGL(build_b_kernel, dim3(MM), dim3(256), 0, stream, gamma, means, Bm);
  for (long i0 = 0; i0 < NN; i0 += rows_cap) {
    long rows = (NN - i0 < rows_cap) ? (NN - i0) : rows_cap;
    hipLaunchKernelGGL(build_a_kernel, dim3(rows / 256), dim3(256), 0, stream,
                       x + (size_t)i0 * DDIM, Am);
    hipLaunchKernelGGL(screen_kernel, dim3(rows / ROWS), dim3(256),
                       ROWS * KSYM * 2, stream,
                       Am, x, gamma, means, weights, Bm, acc, list, count, (int)i0);
  }
  hipLaunchKernelGGL(survivor_kernel, dim3(512), dim3(256), 0, stream,
                     list, count, x, gamma, means, weights, acc);
  hipLaunchKernelGGL(finalize_kernel, dim3(NN / 256), dim3(256), 0, stream,
                     acc, (float*)d_out);
}

// Round 6
// 268.941 us; speedup vs baseline: 4.4274x; 1.2955x over previous
//
#include <hip/hip_runtime.h>
#include <math.h>

// RBF mixture: out[i] = sum_m w_m * exp(-(x_i-mu_m)^T C_m (x_i-mu_m)), C_m = G_m G_m^T
// N=32768, M=2048, D=32.
// Round 6: (a) survivors bucketed by m -> per-m lists, survivor2_kernel stages
// G_m in LDS (kills the per-lane gamma gather that ate ~194us in r5);
// (b) screen pipeline deepened: A prefetch distance 2 (3 slots), B distance 3
// (4 slots) to cover L2 load latency; (c) SCREEN 160->144.

#define NN 32768
#define MM 2048
#define DDIM 32
#define KSYM 576           // 528 triangle + 32 cross + 2 const + 14 pad = 18*32
#define ROWS 64            // i-rows per screen block
#define KSTEPS 18
#define SCREEN 144.0f
#define MCAP 2048          // per-m survivor list capacity (ushort entries)
#define FCAP 1000000       // fallback flat list capacity

typedef __attribute__((ext_vector_type(8))) short short8;
typedef __attribute__((ext_vector_type(4))) float floatx4;

__device__ __forceinline__ unsigned int to_bf16(float f) {
  union { float f; unsigned int u; } x; x.f = f;
  return (x.u + 0x7fffu + ((x.u >> 16) & 1u)) >> 16;   // RNE, finite inputs only
}

// slot s in [0,528) -> (d,f), d<=f (runtime version, build_b only)
__device__ __forceinline__ void slot_df(int s, int* dd, int* ff) {
  int d = 0, b = 0;
  while (b + (DDIM - d) <= s) { b += DDIM - d; ++d; }
  *dd = d; *ff = d + (s - b);
}

// ---------------------------------------------------------------------------
// Kernel 1: bf16 B-matrix [M][KSYM]:
//  [0,528): C_dd diag / 2*C_df offdiag (triangle, d-major); [528,560): -2*(C mu);
//  560: c_hi, 561: c_lo (c = mu^T C mu); [562,576): 0
// ---------------------------------------------------------------------------
__global__ __launch_bounds__(256) void build_b_kernel(
    const float* __restrict__ gamma, const float* __restrict__ means,
    unsigned short* __restrict__ Bm) {
  __shared__ float G[DDIM][DDIM + 1];
  __shared__ float C[DDIM][DDIM + 1];
  __shared__ float bv[DDIM];
  __shared__ float cc;
  const int m = blockIdx.x;
  const int t = threadIdx.x;
  const float* g = gamma + (size_t)m * DDIM * DDIM;
  for (int l = t; l < DDIM * DDIM; l += 256) G[l >> 5][l & 31] = g[l];
  __syncthreads();
  const float* mu = means + m * DDIM;
  for (int l = t; l < DDIM * DDIM; l += 256) {
    int d = l >> 5, f = l & 31;
    float c = 0.f;
#pragma unroll
    for (int e = 0; e < DDIM; ++e) c += G[d][e] * G[f][e];
    C[d][f] = c;
  }
  __syncthreads();
  if (t < DDIM) {
    float b = 0.f;
#pragma unroll
    for (int f = 0; f < DDIM; ++f) b += C[t][f] * mu[f];
    bv[t] = b;
  }
  __syncthreads();
  if (t == 0) {
    float c = 0.f;
#pragma unroll
    for (int d = 0; d < DDIM; ++d) c += bv[d] * mu[d];
    cc = c;
  }
  __syncthreads();
  unsigned short* brow = Bm + (size_t)m * KSYM;
  for (int s = t; s < KSYM; s += 256) {
    float val;
    if (s < 528) {
      int d, f; slot_df(s, &d, &f);
      val = (d == f) ? C[d][d] : 2.f * C[d][f];
    } else if (s < 560) {
      val = -2.f * bv[s - 528];
    } else if (s == 560) {
      val = cc;
    } else if (s == 561) {
      unsigned int hi = to_bf16(cc);
      union { unsigned int u; float f; } xh; xh.u = hi << 16;
      val = cc - xh.f;
    } else {
      val = 0.f;
    }
    brow[s] = (unsigned short)to_bf16(val);
  }
}

// ---------------------------------------------------------------------------
// Kernel 2: bf16 A-matrix [rows][KSYM]. One thread per row; compile-time (d,f).
// ---------------------------------------------------------------------------
__global__ __launch_bounds__(256) void build_a_kernel(
    const float* __restrict__ x, unsigned short* __restrict__ Am) {
  const int row = blockIdx.x * 256 + threadIdx.x;
  float v[DDIM];
#pragma unroll
  for (int q = 0; q < 8; ++q)
    *(floatx4*)&v[q * 4] = *(const floatx4*)(x + (size_t)row * DDIM + q * 4);
  unsigned short* arow = Am + (size_t)row * KSYM;
  unsigned int u0 = 0, u1 = 0, u2 = 0, u3 = 0;
  int s = 0;
#pragma unroll
  for (int d = 0; d < DDIM; ++d) {
#pragma unroll
    for (int f = d; f < DDIM; ++f) {
      unsigned int b = to_bf16(v[d] * v[f]);
      int sl = (s & 7) >> 1;
      unsigned int add = ((s & 1) == 0) ? b : (b << 16);
      if (sl == 0) u0 = ((s & 1) == 0) ? add : (u0 | add);
      else if (sl == 1) u1 = ((s & 1) == 0) ? add : (u1 | add);
      else if (sl == 2) u2 = ((s & 1) == 0) ? add : (u2 | add);
      else              u3 = ((s & 1) == 0) ? add : (u3 | add);
      if ((s & 7) == 7) {
        uint4 o; o.x = u0; o.y = u1; o.z = u2; o.w = u3;
        *(uint4*)(arow + (s - 7)) = o;
      }
      ++s;
    }
  }
#pragma unroll
  for (int f = 0; f < DDIM; f += 8) {
    uint4 o;
    o.x = to_bf16(v[f + 0]) | (to_bf16(v[f + 1]) << 16);
    o.y = to_bf16(v[f + 2]) | (to_bf16(v[f + 3]) << 16);
    o.z = to_bf16(v[f + 4]) | (to_bf16(v[f + 5]) << 16);
    o.w = to_bf16(v[f + 6]) | (to_bf16(v[f + 7]) << 16);
    *(uint4*)(arow + 528 + f) = o;
  }
  uint4 one; one.x = 0x3f803f80u; one.y = 0u; one.z = 0u; one.w = 0u;
  *(uint4*)(arow + 560) = one;
  uint4 z; z.x = 0u; z.y = 0u; z.z = 0u; z.w = 0u;
  *(uint4*)(arow + 568) = z;
}

// ---------------------------------------------------------------------------
// Exact scalar path (fallback list only).
// ---------------------------------------------------------------------------
__device__ __noinline__ double survivor_contrib(
    int m, const float* __restrict__ gamma, const float* __restrict__ means,
    const float* __restrict__ weights, const float* __restrict__ xrow) {
  const float* mu = means + m * DDIM;
  float v[DDIM];
#pragma unroll
  for (int d = 0; d < DDIM; ++d) v[d] = xrow[d] - mu[d];
  const float* g = gamma + (size_t)m * DDIM * DDIM;
  float Dex = 0.f;
  for (int e = 0; e < DDIM; ++e) {
    float y = 0.f;
#pragma unroll
    for (int d = 0; d < DDIM; ++d) y += g[d * DDIM + e] * v[d];
    Dex += y * y;
  }
  return (double)weights[m] * exp(-(double)Dex);
}

// ---------------------------------------------------------------------------
// Kernel 3: barrier-free bf16 MFMA screen. 64-row A-tile in 73.7 KB dynamic
// LDS (XOR chunk swizzle), waves sweep M with B global->VGPR (L2-resident).
// Pipeline: A prefetch distance 2 (3 slots), B distance 3 (4 slots).
// Survivors -> per-m bucketed lists (i as ushort); overflow -> flat list.
// ---------------------------------------------------------------------------
__global__ __launch_bounds__(256, 2) void screen_kernel(
    const unsigned short* __restrict__ Am, const unsigned short* __restrict__ Bm,
    unsigned int* __restrict__ mcnt, unsigned short* __restrict__ mlist,
    unsigned int* __restrict__ flist, unsigned int* __restrict__ fcount,
    int i_base) {
  extern __shared__ __align__(16) unsigned short As[];   // ROWS * KSYM
  const int t = threadIdx.x;
  const int i0 = blockIdx.x * ROWS;
  const int lane = t & 63, w = t >> 6;
  const int lrow = lane & 15, quad = lane >> 4;

  // stage A tile once: 64 rows x 72 chunks(16B); swizzle slot = c^(r&7)
#pragma unroll
  for (int it = 0; it < 18; ++it) {
    int g = it * 256 + t;
    int r = g / 72, c = g - r * 72;
    uint4 v = *(const uint4*)(Am + (size_t)(i0 + r) * KSYM + c * 8);
    int cs = (c & ~7) | ((c & 7) ^ (r & 7));
    *(uint4*)&As[r * KSYM + cs * 8] = v;
  }
  __syncthreads();

  for (int g8 = 0; g8 < 8; ++g8) {
    const int m0 = (g8 * 4 + w) * 64;               // this wave's m-quad base
    const unsigned short* bb0 = Bm + (size_t)(m0 +  0 + lrow) * KSYM + quad * 8;
    const unsigned short* bb1 = Bm + (size_t)(m0 + 16 + lrow) * KSYM + quad * 8;
    const unsigned short* bb2 = Bm + (size_t)(m0 + 32 + lrow) * KSYM + quad * 8;
    const unsigned short* bb3 = Bm + (size_t)(m0 + 48 + lrow) * KSYM + quad * 8;

    floatx4 acc[4][4] = {};                          // [ti][mj]
    short8 af[3][4], bf[4][4];

#pragma unroll
    for (int pp = 0; pp < 2; ++pp) {                 // A: ksteps 0,1
#pragma unroll
      for (int ti = 0; ti < 4; ++ti) {
        int r = ti * 16 + lrow;
        int c = pp * 4 + quad;
        int cs = (c & ~7) | ((c & 7) ^ (r & 7));
        af[pp][ti] = *(const short8*)&As[r * KSYM + cs * 8];
      }
    }
#pragma unroll
    for (int pp = 0; pp < 3; ++pp) {                 // B: ksteps 0,1,2
      bf[pp][0] = *(const short8*)(bb0 + pp * 32);
      bf[pp][1] = *(const short8*)(bb1 + pp * 32);
      bf[pp][2] = *(const short8*)(bb2 + pp * 32);
      bf[pp][3] = *(const short8*)(bb3 + pp * 32);
    }

#pragma unroll
    for (int kk = 0; kk < KSTEPS; ++kk) {
      if (kk + 2 < KSTEPS) {                         // A prefetch, distance 2
        const int sa = (kk + 2) % 3;
#pragma unroll
        for (int ti = 0; ti < 4; ++ti) {
          int r = ti * 16 + lrow;
          int c = (kk + 2) * 4 + quad;
          int cs = (c & ~7) | ((c & 7) ^ (r & 7));
          af[sa][ti] = *(const short8*)&As[r * KSYM + cs * 8];
        }
      }
      if (kk + 3 < KSTEPS) {                         // B prefetch, distance 3
        const int sb = (kk + 3) & 3;
        bf[sb][0] = *(const short8*)(bb0 + (kk + 3) * 32);
        bf[sb][1] = *(const short8*)(bb1 + (kk + 3) * 32);
        bf[sb][2] = *(const short8*)(bb2 + (kk + 3) * 32);
        bf[sb][3] = *(const short8*)(bb3 + (kk + 3) * 32);
      }
      const int ca = kk % 3, cb = kk & 3;
#pragma unroll
      for (int ti = 0; ti < 4; ++ti)
#pragma unroll
        for (int mj = 0; mj < 4; ++mj)
          acc[ti][mj] = __builtin_amdgcn_mfma_f32_16x16x32_bf16(
              af[ca][ti], bf[cb][mj], acc[ti][mj], 0, 0, 0);
    }

    // screen & emit survivors (rare) into per-m buckets
#pragma unroll
    for (int ti = 0; ti < 4; ++ti)
#pragma unroll
      for (int mj = 0; mj < 4; ++mj)
#pragma unroll
        for (int r = 0; r < 4; ++r) {
          float Dt = acc[ti][mj][r];
          if (Dt < SCREEN) {
            int gi = i_base + i0 + ti * 16 + quad * 4 + r;
            int gm = m0 + mj * 16 + lrow;
            unsigned int idx = atomicAdd(&mcnt[gm], 1u);
            if (idx < MCAP) {
              mlist[(size_t)gm * MCAP + idx] = (unsigned short)gi;
            } else {
              unsigned int fi = atomicAdd(fcount, 1u);
              if (fi < FCAP)
                flist[fi] = ((unsigned int)gi << 11) | (unsigned int)gm;
            }
          }
        }
  }
}

// ---------------------------------------------------------------------------
// Kernel 4: per-m survivor processing. Block = m. G_m^T staged in LDS
// (broadcast-read), survivors' x rows loaded per-thread. Exact fp32 D,
// double-accumulated into acc[i].
// ---------------------------------------------------------------------------
__global__ __launch_bounds__(256) void survivor2_kernel(
    const unsigned int* __restrict__ mcnt, const unsigned short* __restrict__ mlist,
    const float* __restrict__ x, const float* __restrict__ gamma,
    const float* __restrict__ means, const float* __restrict__ weights,
    double* __restrict__ acc_out) {
  __shared__ float Gt[DDIM][DDIM + 1];   // Gt[e][d] = G[d][e]
  __shared__ float mu[DDIM];
  const int m = blockIdx.x;
  const int t = threadIdx.x;
  unsigned int cnt = mcnt[m];
  if (cnt > MCAP) cnt = MCAP;
  if (cnt == 0) return;
  const float* g = gamma + (size_t)m * DDIM * DDIM;
  for (int l = t; l < DDIM * DDIM; l += 256) Gt[l & 31][l >> 5] = g[l];
  if (t < DDIM) mu[t] = means[m * DDIM + t];
  __syncthreads();
  const float wm = weights[m];
  for (unsigned int s = t; s < cnt; s += 256) {
    int gi = mlist[(size_t)m * MCAP + s];
    float v[DDIM];
#pragma unroll
    for (int q = 0; q < 8; ++q) {
      floatx4 xv = *(const floatx4*)(x + (size_t)gi * DDIM + q * 4);
      v[q * 4 + 0] = xv.x - mu[q * 4 + 0];
      v[q * 4 + 1] = xv.y - mu[q * 4 + 1];
      v[q * 4 + 2] = xv.z - mu[q * 4 + 2];
      v[q * 4 + 3] = xv.w - mu[q * 4 + 3];
    }
    float Dex = 0.f;
#pragma unroll
    for (int e = 0; e < DDIM; ++e) {
      float y = 0.f;
#pragma unroll
      for (int d = 0; d < DDIM; ++d) y += Gt[e][d] * v[d];
      Dex += y * y;
    }
    atomicAdd(&acc_out[gi], (double)wm * exp(-(double)Dex));
  }
}

// ---------------------------------------------------------------------------
// Kernel 5: fallback flat list (bucket overflow only; normally empty).
// ---------------------------------------------------------------------------
__global__ __launch_bounds__(256) void survivor_fallback_kernel(
    const unsigned int* __restrict__ flist, const unsigned int* __restrict__ fcount,
    const float* __restrict__ x, const float* __restrict__ gamma,
    const float* __restrict__ means, const float* __restrict__ weights,
    double* __restrict__ acc_out) {
  unsigned int total = *fcount;
  if (total > FCAP) total = FCAP;
  for (unsigned int idx = blockIdx.x * 256 + threadIdx.x; idx < total;
       idx += gridDim.x * 256) {
    unsigned int p = flist[idx];
    int gi = (int)(p >> 11), gm = (int)(p & 2047u);
    double c = survivor_contrib(gm, gamma, means, weights, x + (size_t)gi * DDIM);
    atomicAdd(&acc_out[gi], c);
  }
}

__global__ __launch_bounds__(256) void finalize_kernel(
    const double* __restrict__ acc, float* __restrict__ out) {
  int i = blockIdx.x * 256 + threadIdx.x;
  out[i] = (float)acc[i];
}

extern "C" void kernel_launch(void* const* d_in, const int* in_sizes, int n_in,
                              void* d_out, int out_size, void* d_ws, size_t ws_size,
                              hipStream_t stream) {
  (void)in_sizes; (void)n_in; (void)out_size;
  const float* x       = (const float*)d_in[0];   // [N][32]
  const float* gamma   = (const float*)d_in[1];   // [M][32][32]
  const float* means   = (const float*)d_in[2];   // [M][32]
  const float* weights = (const float*)d_in[3];   // [M]

  char* p = (char*)d_ws;
  double* acc          = (double*)p;            p += (size_t)NN * 8;       // zeroed
  unsigned int* fcount = (unsigned int*)p;      p += 16;                   // zeroed
  unsigned int* mcnt   = (unsigned int*)p;      p += (size_t)MM * 4;       // zeroed
  unsigned short* mlist= (unsigned short*)p;    p += (size_t)MM * MCAP * 2;
  unsigned int* flist  = (unsigned int*)p;      p += (size_t)FCAP * 4;
  unsigned short* Bm   = (unsigned short*)p;    p += (size_t)MM * KSYM * 2;
  unsigned short* Am   = (unsigned short*)p;
  const size_t fixed = (size_t)(p - (char*)d_ws);
  const size_t zero_bytes = (size_t)NN * 8 + 16 + (size_t)MM * 4;
  if (ws_size < fixed + (size_t)256 * KSYM * 2) return;

  size_t avail = ws_size - fixed;
  long rows_cap = (long)(avail / ((size_t)KSYM * 2));
  rows_cap = (rows_cap / 256) * 256;
  if (rows_cap > NN) rows_cap = NN;

  (void)hipFuncSetAttribute((const void*)screen_kernel,
                            hipFuncAttributeMaxDynamicSharedMemorySize,
                            ROWS * KSYM * 2);

  hipMemsetAsync(d_ws, 0, zero_bytes, stream);   // acc + fcount + mcnt
  hipLaunchKernelGGL(build_b_kernel, dim3(MM), dim3(256), 0, stream, gamma, means, Bm);
  for (long i0 = 0; i0 < NN; i0 += rows_cap) {
    long rows = (NN - i0 < rows_cap) ? (NN - i0) : rows_cap;
    hipLaunchKernelGGL(build_a_kernel, dim3(rows / 256), dim3(256), 0, stream,
                       x + (size_t)i0 * DDIM, Am);
    hipLaunchKernelGGL(screen_kernel, dim3(rows / ROWS), dim3(256),
                       ROWS * KSYM * 2, stream,
                       Am, Bm, mcnt, mlist, flist, fcount, (int)i0);
  }
  hipLaunchKernelGGL(survivor2_kernel, dim3(MM), dim3(256), 0, stream,
                     mcnt, mlist, x, gamma, means, weights, acc);
  hipLaunchKernelGGL(survivor_fallback_kernel, dim3(256), dim3(256), 0, stream,
                     flist, fcount, x, gamma, means, weights, acc);
  hipLaunchKernelGGL(finalize_kernel, dim3(NN / 256), dim3(256), 0, stream,
                     acc, (float*)d_out);
}

// Round 7
// 247.772 us; speedup vs baseline: 4.8057x; 1.0854x over previous
//
#include <hip/hip_runtime.h>
#include <math.h>

// RBF mixture: out[i] = sum_m w_m * exp(-(x_i-mu_m)^T C_m (x_i-mu_m)), C_m = G_m G_m^T
// N=32768, M=2048, D=32.
// Round 7: (a) screen blocks 256->512 threads (8 waves): same 73.7 KB LDS
// A-tile, 2 blocks/CU -> 16 waves/CU (4/SIMD) for TLP latency hiding (r6
// showed the compiler sinks manual prefetch; per-wave ILP is dead);
// (b) A generated in-kernel into swizzled LDS (constexpr (d,f) table) --
// kills build_a kernel + 37.7 MB global round-trip; (c) survivor exp via
// exp2f + ldexp (no double exp); SCREEN 144->120.

#define NN 32768
#define MM 2048
#define DDIM 32
#define KSYM 576           // 528 triangle + 32 cross + 2 const + 14 pad = 18*32
#define ROWS 64            // i-rows per screen block
#define KSTEPS 18
#define SCREEN 120.0f
#define MCAP 2048          // per-m survivor list capacity (ushort entries)
#define FCAP 1000000       // fallback flat list capacity

typedef __attribute__((ext_vector_type(8))) short short8;
typedef __attribute__((ext_vector_type(4))) float floatx4;

__device__ __forceinline__ unsigned int to_bf16(float f) {
  union { float f; unsigned int u; } x; x.f = f;
  return (x.u + 0x7fffu + ((x.u >> 16) & 1u)) >> 16;   // RNE, finite inputs only
}

// compile-time slot -> (d,f) table for the packed symmetric layout
struct DFTab { unsigned char d[528]; unsigned char f[528]; };
constexpr DFTab make_df() {
  DFTab t{};
  int s = 0;
  for (int d = 0; d < 32; ++d)
    for (int f = d; f < 32; ++f) {
      t.d[s] = (unsigned char)d; t.f[s] = (unsigned char)f; ++s;
    }
  return t;
}
constexpr DFTab DFT = make_df();

// value of A[row][s] given the row's x values; s must be compile-time
__device__ __forceinline__ float slot_val(const float* v, int s) {
  if (s < 528) return v[DFT.d[s]] * v[DFT.f[s]];
  if (s < 560) return v[s - 528];
  if (s < 562) return 1.f;
  return 0.f;
}

// runtime slot -> (d,f) (build_b only)
__device__ __forceinline__ void slot_df(int s, int* dd, int* ff) {
  int d = 0, b = 0;
  while (b + (DDIM - d) <= s) { b += DDIM - d; ++d; }
  *dd = d; *ff = d + (s - b);
}

// ---------------------------------------------------------------------------
// Kernel 1: bf16 B-matrix [M][KSYM]:
//  [0,528): C_dd diag / 2*C_df offdiag (triangle, d-major); [528,560): -2*(C mu);
//  560: c_hi, 561: c_lo (c = mu^T C mu); [562,576): 0
// ---------------------------------------------------------------------------
__global__ __launch_bounds__(256) void build_b_kernel(
    const float* __restrict__ gamma, const float* __restrict__ means,
    unsigned short* __restrict__ Bm) {
  __shared__ float G[DDIM][DDIM + 1];
  __shared__ float C[DDIM][DDIM + 1];
  __shared__ float bv[DDIM];
  __shared__ float cc;
  const int m = blockIdx.x;
  const int t = threadIdx.x;
  const float* g = gamma + (size_t)m * DDIM * DDIM;
  for (int l = t; l < DDIM * DDIM; l += 256) G[l >> 5][l & 31] = g[l];
  __syncthreads();
  const float* mu = means + m * DDIM;
  for (int l = t; l < DDIM * DDIM; l += 256) {
    int d = l >> 5, f = l & 31;
    float c = 0.f;
#pragma unroll
    for (int e = 0; e < DDIM; ++e) c += G[d][e] * G[f][e];
    C[d][f] = c;
  }
  __syncthreads();
  if (t < DDIM) {
    float b = 0.f;
#pragma unroll
    for (int f = 0; f < DDIM; ++f) b += C[t][f] * mu[f];
    bv[t] = b;
  }
  __syncthreads();
  if (t == 0) {
    float c = 0.f;
#pragma unroll
    for (int d = 0; d < DDIM; ++d) c += bv[d] * mu[d];
    cc = c;
  }
  __syncthreads();
  unsigned short* brow = Bm + (size_t)m * KSYM;
  for (int s = t; s < KSYM; s += 256) {
    float val;
    if (s < 528) {
      int d, f; slot_df(s, &d, &f);
      val = (d == f) ? C[d][d] : 2.f * C[d][f];
    } else if (s < 560) {
      val = -2.f * bv[s - 528];
    } else if (s == 560) {
      val = cc;
    } else if (s == 561) {
      unsigned int hi = to_bf16(cc);
      union { unsigned int u; float f; } xh; xh.u = hi << 16;
      val = cc - xh.f;
    } else {
      val = 0.f;
    }
    brow[s] = (unsigned short)to_bf16(val);
  }
}

// ---------------------------------------------------------------------------
// Exact scalar path (fallback list only).
// ---------------------------------------------------------------------------
__device__ __noinline__ double survivor_contrib(
    int m, const float* __restrict__ gamma, const float* __restrict__ means,
    const float* __restrict__ weights, const float* __restrict__ xrow) {
  const float* mu = means + m * DDIM;
  float v[DDIM];
#pragma unroll
  for (int d = 0; d < DDIM; ++d) v[d] = xrow[d] - mu[d];
  const float* g = gamma + (size_t)m * DDIM * DDIM;
  float Dex = 0.f;
  for (int e = 0; e < DDIM; ++e) {
    float y = 0.f;
#pragma unroll
    for (int d = 0; d < DDIM; ++d) y += g[d * DDIM + e] * v[d];
    Dex += y * y;
  }
  float e2 = -Dex * 1.44269504088896340736f;
  float kf = floorf(e2);
  float mant = exp2f(e2 - kf);
  return ldexp((double)(weights[m] * mant), (int)kf);
}

// ---------------------------------------------------------------------------
// Kernel 3: bf16 MFMA screen. 512 threads (8 waves), 64-row A-tile generated
// in-kernel into 73.7 KB dynamic LDS (XOR chunk swizzle; 0 conflicts verified
// r3-r6). 2 blocks/CU -> 4 waves/SIMD. Wave w sweeps m-quads (g*8+w)*64,
// g=0..3; B frags global->VGPR (B = 2.3 MB, L2-resident). No manual
// pipelining (compiler hoists within its budget; TLP hides latency).
// Frag layout (m89/m97): A/B [row=lane&15][k=quad*8+j]; C/D col=lane&15,
// row=quad*4+reg. Survivors -> per-m bucket lists; overflow -> flat list.
// ---------------------------------------------------------------------------
__global__ __launch_bounds__(512, 4) void screen_kernel(
    const float* __restrict__ x, const unsigned short* __restrict__ Bm,
    unsigned int* __restrict__ mcnt, unsigned short* __restrict__ mlist,
    unsigned int* __restrict__ flist, unsigned int* __restrict__ fcount) {
  extern __shared__ __align__(16) unsigned short As[];   // ROWS * KSYM
  const int t = threadIdx.x;
  const int i0 = blockIdx.x * ROWS;
  const int lane = t & 63, w = t >> 6;                   // w in [0,8)
  const int lrow = lane & 15, quad = lane >> 4;

  // ---- generate A tile into swizzled LDS: row r, slot-block j (72 slots) ----
  {
    const int r = t >> 3, j = t & 7;
    float v[DDIM];
#pragma unroll
    for (int q = 0; q < 8; ++q)
      *(floatx4*)&v[q * 4] = *(const floatx4*)(x + (size_t)(i0 + r) * DDIM + q * 4);
#pragma unroll
    for (int jj = 0; jj < 8; ++jj) {
      if (j == jj) {
#pragma unroll
        for (int cc = 0; cc < 9; ++cc) {
          const int c = jj * 9 + cc;                     // 16B chunk index 0..71
          unsigned int uu[4];
#pragma unroll
          for (int q = 0; q < 4; ++q) {
            const int s0 = c * 8 + q * 2;
            uu[q] = to_bf16(slot_val(v, s0)) | (to_bf16(slot_val(v, s0 + 1)) << 16);
          }
          const int cs = (c & ~7) | ((c & 7) ^ (r & 7));
          uint4 o; o.x = uu[0]; o.y = uu[1]; o.z = uu[2]; o.w = uu[3];
          *(uint4*)&As[r * KSYM + cs * 8] = o;
        }
      }
    }
  }
  __syncthreads();

  for (int g = 0; g < 4; ++g) {
    const int m0 = (g * 8 + w) * 64;                    // this wave's m-quad base
    const unsigned short* bb0 = Bm + (size_t)(m0 +  0 + lrow) * KSYM + quad * 8;
    const unsigned short* bb1 = Bm + (size_t)(m0 + 16 + lrow) * KSYM + quad * 8;
    const unsigned short* bb2 = Bm + (size_t)(m0 + 32 + lrow) * KSYM + quad * 8;
    const unsigned short* bb3 = Bm + (size_t)(m0 + 48 + lrow) * KSYM + quad * 8;

    floatx4 acc[4][4] = {};                              // [ti][mj]
#pragma unroll
    for (int kk = 0; kk < KSTEPS; ++kk) {
      short8 bf[4];
      bf[0] = *(const short8*)(bb0 + kk * 32);
      bf[1] = *(const short8*)(bb1 + kk * 32);
      bf[2] = *(const short8*)(bb2 + kk * 32);
      bf[3] = *(const short8*)(bb3 + kk * 32);
      short8 af[4];
#pragma unroll
      for (int ti = 0; ti < 4; ++ti) {
        int rr = ti * 16 + lrow;
        int c = kk * 4 + quad;
        int cs = (c & ~7) | ((c & 7) ^ (rr & 7));
        af[ti] = *(const short8*)&As[rr * KSYM + cs * 8];
      }
#pragma unroll
      for (int ti = 0; ti < 4; ++ti)
#pragma unroll
        for (int mj = 0; mj < 4; ++mj)
          acc[ti][mj] = __builtin_amdgcn_mfma_f32_16x16x32_bf16(
              af[ti], bf[mj], acc[ti][mj], 0, 0, 0);
    }

    // screen & emit survivors (rare) into per-m buckets
#pragma unroll
    for (int ti = 0; ti < 4; ++ti)
#pragma unroll
      for (int mj = 0; mj < 4; ++mj)
#pragma unroll
        for (int r = 0; r < 4; ++r) {
          float Dt = acc[ti][mj][r];
          if (Dt < SCREEN) {
            int gi = i0 + ti * 16 + quad * 4 + r;
            int gm = m0 + mj * 16 + lrow;
            unsigned int idx = atomicAdd(&mcnt[gm], 1u);
            if (idx < MCAP) {
              mlist[(size_t)gm * MCAP + idx] = (unsigned short)gi;
            } else {
              unsigned int fi = atomicAdd(fcount, 1u);
              if (fi < FCAP)
                flist[fi] = ((unsigned int)gi << 11) | (unsigned int)gm;
            }
          }
        }
  }
}

// ---------------------------------------------------------------------------
// Kernel 4: per-m survivor processing. Block = m. G_m^T staged in LDS
// (broadcast-read). Exact fp32 D; exp via exp2f mantissa + ldexp into double.
// ---------------------------------------------------------------------------
__global__ __launch_bounds__(256) void survivor2_kernel(
    const unsigned int* __restrict__ mcnt, const unsigned short* __restrict__ mlist,
    const float* __restrict__ x, const float* __restrict__ gamma,
    const float* __restrict__ means, const float* __restrict__ weights,
    double* __restrict__ acc_out) {
  __shared__ float Gt[DDIM][DDIM + 1];   // Gt[e][d] = G[d][e]
  __shared__ float mu[DDIM];
  const int m = blockIdx.x;
  const int t = threadIdx.x;
  unsigned int cnt = mcnt[m];
  if (cnt > MCAP) cnt = MCAP;
  if (cnt == 0) return;
  const float* g = gamma + (size_t)m * DDIM * DDIM;
  for (int l = t; l < DDIM * DDIM; l += 256) Gt[l & 31][l >> 5] = g[l];
  if (t < DDIM) mu[t] = means[m * DDIM + t];
  __syncthreads();
  const float wm = weights[m];
  for (unsigned int s = t; s < cnt; s += 256) {
    int gi = mlist[(size_t)m * MCAP + s];
    float v[DDIM];
#pragma unroll
    for (int q = 0; q < 8; ++q) {
      floatx4 xv = *(const floatx4*)(x + (size_t)gi * DDIM + q * 4);
      v[q * 4 + 0] = xv.x - mu[q * 4 + 0];
      v[q * 4 + 1] = xv.y - mu[q * 4 + 1];
      v[q * 4 + 2] = xv.z - mu[q * 4 + 2];
      v[q * 4 + 3] = xv.w - mu[q * 4 + 3];
    }
    float Dex = 0.f;
#pragma unroll
    for (int e = 0; e < DDIM; ++e) {
      float y = 0.f;
#pragma unroll
      for (int d = 0; d < DDIM; ++d) y += Gt[e][d] * v[d];
      Dex += y * y;
    }
    float e2 = -Dex * 1.44269504088896340736f;
    float kf = floorf(e2);
    float mant = exp2f(e2 - kf);
    atomicAdd(&acc_out[gi], ldexp((double)(wm * mant), (int)kf));
  }
}

// ---------------------------------------------------------------------------
// Kernel 5: fallback flat list (bucket overflow only; normally empty).
// ---------------------------------------------------------------------------
__global__ __launch_bounds__(256) void survivor_fallback_kernel(
    const unsigned int* __restrict__ flist, const unsigned int* __restrict__ fcount,
    const float* __restrict__ x, const float* __restrict__ gamma,
    const float* __restrict__ means, const float* __restrict__ weights,
    double* __restrict__ acc_out) {
  unsigned int total = *fcount;
  if (total > FCAP) total = FCAP;
  for (unsigned int idx = blockIdx.x * 256 + threadIdx.x; idx < total;
       idx += gridDim.x * 256) {
    unsigned int p = flist[idx];
    int gi = (int)(p >> 11), gm = (int)(p & 2047u);
    double c = survivor_contrib(gm, gamma, means, weights, x + (size_t)gi * DDIM);
    atomicAdd(&acc_out[gi], c);
  }
}

__global__ __launch_bounds__(256) void finalize_kernel(
    const double* __restrict__ acc, float* __restrict__ out) {
  int i = blockIdx.x * 256 + threadIdx.x;
  out[i] = (float)acc[i];
}

extern "C" void kernel_launch(void* const* d_in, const int* in_sizes, int n_in,
                              void* d_out, int out_size, void* d_ws, size_t ws_size,
                              hipStream_t stream) {
  (void)in_sizes; (void)n_in; (void)out_size;
  const float* x       = (const float*)d_in[0];   // [N][32]
  const float* gamma   = (const float*)d_in[1];   // [M][32][32]
  const float* means   = (const float*)d_in[2];   // [M][32]
  const float* weights = (const float*)d_in[3];   // [M]

  char* p = (char*)d_ws;
  double* acc          = (double*)p;            p += (size_t)NN * 8;       // zeroed
  unsigned int* fcount = (unsigned int*)p;      p += 16;                   // zeroed
  unsigned int* mcnt   = (unsigned int*)p;      p += (size_t)MM * 4;       // zeroed
  unsigned short* mlist= (unsigned short*)p;    p += (size_t)MM * MCAP * 2;
  unsigned int* flist  = (unsigned int*)p;      p += (size_t)FCAP * 4;
  unsigned short* Bm   = (unsigned short*)p;    p += (size_t)MM * KSYM * 2;
  const size_t needed = (size_t)(p - (char*)d_ws);
  const size_t zero_bytes = (size_t)NN * 8 + 16 + (size_t)MM * 4;
  if (ws_size < needed) return;

  (void)hipFuncSetAttribute((const void*)screen_kernel,
                            hipFuncAttributeMaxDynamicSharedMemorySize,
                            ROWS * KSYM * 2);

  hipMemsetAsync(d_ws, 0, zero_bytes, stream);   // acc + fcount + mcnt
  hipLaunchKernelGGL(build_b_kernel, dim3(MM), dim3(256), 0, stream, gamma, means, Bm);
  hipLaunchKernelGGL(screen_kernel, dim3(NN / ROWS), dim3(512),
                     ROWS * KSYM * 2, stream,
                     x, Bm, mcnt, mlist, flist, fcount);
  hipLaunchKernelGGL(survivor2_kernel, dim3(MM), dim3(256), 0, stream,
                     mcnt, mlist, x, gamma, means, weights, acc);
  hipLaunchKernelGGL(survivor_fallback_kernel, dim3(256), dim3(256), 0, stream,
                     flist, fcount, x, gamma, means, weights, acc);
  hipLaunchKernelGGL(finalize_kernel, dim3(NN / 256), dim3(256), 0, stream,
                     acc, (float*)d_out);
}